// Round 10
// baseline (194.657 us; speedup 1.0000x reference)
//
#include <hip/hip_runtime.h>
#include <math.h>

// Problem constants
#define N    130
#define NN   (130*130)       // 16900
#define NNN  (130*130*130)   // 2197000
#define NQ4  (NNN/4)         // 549250
#define NCH  12
#define XN   128
#define XNN  (XN*XN)

// R10 tiling: NO LDS, NO BARRIERS in the main loop.
// Block = 16 lanes (12 valid w, +-2 DPP halo) x 16 h-rows (ALL valid outputs).
// Each block walks a 13-plane d strip. h-box is computed IN-THREAD from 5
// direct taps (L1-resident), w-box via DPP, d-box via the register ring.
#define WT   11              // w tiles: 11*12 = 132 >= 130
#define HT   9               // h tiles: 9*16 = 144 >= 130
#define DSEGS 10             // d strips: 10*13 = 130 exactly
#define NWG  (WT*HT*DSEGS)   // 990 blocks

typedef float f32x4 __attribute__((ext_vector_type(4)));

// DPP lane-shift within 16-lane rows (VALU pipe).
template <int CTRL>
__device__ __forceinline__ float dppf(float v) {
    return __int_as_float(__builtin_amdgcn_update_dpp(
        0, __float_as_int(v), CTRL, 0xF, 0xF, true));
}
#define W5(v) ((v) + dppf<0x111>(v) + dppf<0x112>(v) \
                   + dppf<0x101>(v) + dppf<0x102>(v))

// ---------------------------------------------------------------------------
// Fused kernel: conv-diff^2 + 5x5x5 replicated box + channel min/mean + exp.
//
// 12 channels = 12 orthogonal pairs of 6 shared neighbour values
//   Y0=d-, Y1=d+, Y2=h-, Y3=h+, Y4=w-, Y5=w+   (dilation-2 face neighbours)
// Per-dim addressing in box coords c in [0,129] (verified vs SH tables):
//   class  1 (center): ix = clamp(c-1,0,127), always valid
//   class -1:          ix = clamp(c-3,0,127), masked iff c==0
//   class  3:          ix = clamp(c+1,0,127), masked iff c==129
// Pairs: 0:(Y4,Y0) 1:(Y2,Y0) 2:(Y2,Y4) 3:(Y5,Y0) 4:(Y5,Y2) 5:(Y1,Y4)
//        6:(Y1,Y2) 7:(Y1,Y5) 8:(Y3,Y0) 9:(Y3,Y4) 10:(Y3,Y5) 11:(Y3,Y1)
//
// R10 vs R9 (informed by R8 ablation MODE1=5us + R9 barrier-cost bracket):
// the per-d-plane block-wide LDS h-exchange (the ~90us convoy in EVERY
// previous ~100us variant) is REMOVED. Box_h and Box_w commute, so each
// thread h-boxes diff^2 in-registers from 5 direct taps (30 loads/step,
// L1-resident rows shared across the block), then w-boxes ONCE via DPP.
// Main loop has zero LDS ops and zero barriers; waves run free.
// ---------------------------------------------------------------------------
__global__ __launch_bounds__(256) void k_fused(const float* __restrict__ x,
                                               float* __restrict__ Cout,
                                               float* __restrict__ MV,
                                               double* __restrict__ acc,
                                               unsigned* __restrict__ gmm) {
    const int tid = threadIdx.x;
    const int wl  = tid & 15;
    const int r   = tid >> 4;

    const int b    = blockIdx.x;
    const int wt   = b % WT;
    const int rest = b / WT;
    const int ht   = rest % HT;
    const int ds   = rest / HT;

    const int W0 = wt * 12;
    const int H0 = ht * 16;
    const int D0 = ds * 13;

    const int  w_gl = W0 + wl - 2;                 // global w (+-2 DPP halo)
    const int  bw   = min(max(w_gl, 0), 129);      // edge-clamped box col
    const int  oh   = H0 + r;                      // output row (0..143)
    const bool valid = (wl >= 2) && (wl < 14) && (w_gl < N) && (oh < N);

    // w-dim (thread-invariant)
    const int   iwc  = min(max(bw - 1, 0), 127);
    const int   iwm  = min(max(bw - 3, 0), 127);
    const int   iwp  = min(bw + 1, 127);
    const float fw_m = (bw >= 1)   ? 1.0f : 0.0f;
    const float fw_p = (bw <= 128) ? 1.0f : 0.0f;

    // per-h-tap precompute (thread-invariant across d): box row ch, then
    // the two-stage clamp (ch first!) — required for correct oh=128,129 edges.
    int   oc[5], om[5], op[5], o4[5], o5[5];
    float fhm[5], fhp[5];
    #pragma unroll
    for (int k = 0; k < 5; ++k) {
        const int ch = min(max(oh - 2 + k, 0), 129);
        const int rc = min(max(ch - 1, 0), 127);
        const int rm = min(max(ch - 3, 0), 127);
        const int rp = min(ch + 1, 127);
        oc[k] = rc * XN + iwc;
        om[k] = rm * XN + iwc;
        op[k] = rp * XN + iwc;
        o4[k] = rc * XN + iwm;
        o5[k] = rc * XN + iwp;
        fhm[k] = (ch >= 1)   ? 1.0f : 0.0f;
        fhp[k] = (ch <= 128) ? 1.0f : 0.0f;
    }

    f32x4 ring[5][3];                   // 5-deep d ring, 12 ch as 3x f32x4
    float lsum  = 0.0f;
    float mn_mv = INFINITY, mx_mv = 0.0f;
    int   voxoff = D0 * NN + oh * N + (valid ? w_gl : 0);

#define STEP(IT, SLOT, DOUT) do {                                             \
    const int dc  = min(max(D0 - 2 + (IT), 0), 129);                          \
    const float* pc = x + (size_t)(min(max(dc - 1, 0), 127)) * XNN;           \
    const float* pm = x + (size_t)(min(max(dc - 3, 0), 127)) * XNN;           \
    const float* pp = x + (size_t)(min(dc + 1, 127)) * XNN;                   \
    const float fdm = (dc >= 1)   ? 1.0f : 0.0f;                              \
    const float fdp = (dc <= 128) ? 1.0f : 0.0f;                              \
    float HS[12];                                                             \
    _Pragma("unroll") for (int z = 0; z < 12; ++z) HS[z] = 0.0f;              \
    _Pragma("unroll") for (int k = 0; k < 5; ++k) {                           \
        const float y0 = pm[oc[k]] * fdm;                                     \
        const float y1 = pp[oc[k]] * fdp;                                     \
        const float y2 = pc[om[k]] * fhm[k];                                  \
        const float y3 = pc[op[k]] * fhp[k];                                  \
        const float y4 = pc[o4[k]] * fw_m;                                    \
        const float y5 = pc[o5[k]] * fw_p;                                    \
        float t;                                                              \
        t = y4 - y0; HS[0]  += t * t;  t = y2 - y0; HS[1]  += t * t;          \
        t = y2 - y4; HS[2]  += t * t;  t = y5 - y0; HS[3]  += t * t;          \
        t = y5 - y2; HS[4]  += t * t;  t = y1 - y4; HS[5]  += t * t;          \
        t = y1 - y2; HS[6]  += t * t;  t = y1 - y5; HS[7]  += t * t;          \
        t = y3 - y0; HS[8]  += t * t;  t = y3 - y4; HS[9]  += t * t;          \
        t = y3 - y5; HS[10] += t * t;  t = y3 - y1; HS[11] += t * t;          \
    }                                                                         \
    /* Box_w of the h-boxed values (boxes commute): 4 DPP adds per channel */ \
    _Pragma("unroll") for (int z = 0; z < 12; ++z) HS[z] = W5(HS[z]);         \
    ring[SLOT][0] = (f32x4){HS[0], HS[1], HS[2],  HS[3]};                     \
    ring[SLOT][1] = (f32x4){HS[4], HS[5], HS[6],  HS[7]};                     \
    ring[SLOT][2] = (f32x4){HS[8], HS[9], HS[10], HS[11]};                    \
    if (DOUT) {                                                               \
        f32x4 sg[3];                                                          \
        _Pragma("unroll") for (int g = 0; g < 3; ++g) {                       \
            f32x4 a = ring[0][g];                                             \
            a += ring[1][g]; a += ring[2][g];                                 \
            a += ring[3][g]; a += ring[4][g];                                 \
            sg[g] = a * (1.0f / 125.0f);                                      \
        }                                                                     \
        float sv[12];                                                         \
        _Pragma("unroll") for (int g = 0; g < 3; ++g) {                       \
            sv[4*g+0] = sg[g].x; sv[4*g+1] = sg[g].y;                         \
            sv[4*g+2] = sg[g].z; sv[4*g+3] = sg[g].w;                         \
        }                                                                     \
        float mn = sv[0], tt = sv[0];                                         \
        _Pragma("unroll") for (int z = 1; z < 12; ++z) {                      \
            mn = fminf(mn, sv[z]); tt += sv[z];                               \
        }                                                                     \
        if (valid) {                                                          \
            const float mvar = tt * (1.0f / 12.0f) - mn;                      \
            const float inv  = 1.0f / fmaxf(mvar, 1e-20f);                    \
            _Pragma("unroll") for (int z = 0; z < 12; ++z)                    \
                Cout[(size_t)z * NNN + (unsigned)voxoff] =                    \
                    __expf(-(sv[z] - mn) * inv);                              \
            MV[(unsigned)voxoff] = mvar;                                      \
            lsum += mvar;                                                     \
            mn_mv = fminf(mn_mv, mvar);                                       \
            mx_mv = fmaxf(mx_mv, mvar);                                       \
            voxoff += NN;                                                     \
        }                                                                     \
    }                                                                         \
} while (0)

    // warmup: fill ring slots 0..3 (box planes D0-2 .. D0+1, clamped)
    STEP(0, 0, false);
    STEP(1, 1, false);
    STEP(2, 2, false);
    STEP(3, 3, false);
    // main: 13 output planes; ring slots compile-time (base = 4 mod 5)
    STEP(4, 4, true);   STEP(5, 0, true);   STEP(6, 1, true);
    STEP(7, 2, true);   STEP(8, 3, true);
    STEP(9, 4, true);   STEP(10, 0, true);  STEP(11, 1, true);
    STEP(12, 2, true);  STEP(13, 3, true);
    STEP(14, 4, true);  STEP(15, 0, true);  STEP(16, 1, true);
#undef STEP

    // block reductions: sum, min, max of mvar (epilogue only; tiny LDS)
    __shared__ float red[256];
    red[tid] = lsum;
    __syncthreads();
    for (int st = 128; st > 0; st >>= 1) {
        if (tid < st) red[tid] += red[tid + st];
        __syncthreads();
    }
    if (tid == 0) atomicAdd(acc, (double)red[0]);
    __syncthreads();
    red[tid] = mn_mv;
    __syncthreads();
    for (int st = 128; st > 0; st >>= 1) {
        if (tid < st) red[tid] = fminf(red[tid], red[tid + st]);
        __syncthreads();
    }
    if (tid == 0) atomicMin(&gmm[0], __float_as_uint(red[0]));
    __syncthreads();
    red[tid] = mx_mv;
    __syncthreads();
    for (int st = 128; st > 0; st >>= 1) {
        if (tid < st) red[tid] = fmaxf(red[tid], red[tid + st]);
        __syncthreads();
    }
    if (tid == 0) atomicMax(&gmm[1], __float_as_uint(red[0]));
}

// zero/init the reduction cells
__global__ void k_zero(double* acc, unsigned* gmm) {
    if (blockIdx.x == 0 && threadIdx.x == 0) {
        *acc = 0.0;
        gmm[0] = 0xFFFFFFFFu;
        gmm[1] = 0u;
    }
}

// k_fix: apply the global-mean clip only where it binds (uniform early-out
// when it never does). Pass 1 wrote out = exp(-mind/max(mvar,1e-20));
// clipped-correct value is out^(mvar_used/mvar_clipped).
__global__ __launch_bounds__(256) void k_fix(float* __restrict__ io,
                                             const float* __restrict__ MV,
                                             const double* __restrict__ acc,
                                             const unsigned* __restrict__ gmm) {
    const float mv_mean = (float)(*acc * (1.0 / (double)NNN));
    const float lo = mv_mean * 0.001f, hi = mv_mean * 1000.0f;
    const float gmin = __uint_as_float(gmm[0]);
    const float gmax = __uint_as_float(gmm[1]);
    if (gmin >= lo && gmax <= hi) return;
    for (int q = blockIdx.x * 256 + threadIdx.x; q < NQ4;
         q += gridDim.x * 256) {
        const f32x4 mv = *((const f32x4*)MV + q);
        #pragma unroll
        for (int k = 0; k < 4; ++k) {
            const float used = fmaxf(mv[k], 1e-20f);
            const float cl   = fminf(fmaxf(mv[k], lo), hi);
            const float e    = used / cl;
            if (fabsf(e - 1.0f) > 1e-6f) {
                const size_t vox = (size_t)q * 4 + k;
                #pragma unroll
                for (int o = 0; o < NCH; ++o) {
                    const float v = io[(size_t)o * NNN + vox];
                    if (v > 0.0f)
                        io[(size_t)o * NNN + vox] = __powf(v, e);
                }
            }
        }
    }
}

extern "C" void kernel_launch(void* const* d_in, const int* in_sizes, int n_in,
                              void* d_out, int out_size, void* d_ws, size_t ws_size,
                              hipStream_t stream) {
    const float* x = (const float*)d_in[0];
    float* out = (float*)d_out;                 // [12,130,130,130] f32
    float* MV  = (float*)d_ws;                  // mvar plane, NNN floats
    double*  acc = (double*)((char*)d_ws + (size_t)NNN * sizeof(float));
    unsigned* gmm = (unsigned*)((char*)d_ws + (size_t)NNN * sizeof(float) + 8);

    k_zero <<<1, 64, 0, stream>>>(acc, gmm);
    k_fused<<<NWG, 256, 0, stream>>>(x, out, MV, acc, gmm);  // 990 blocks
    k_fix  <<<1024, 256, 0, stream>>>(out, MV, acc, gmm);
}

// Round 11
// 163.873 us; speedup vs baseline: 1.1879x; 1.1879x over previous
//
#include <hip/hip_runtime.h>
#include <math.h>

// Problem constants
#define N    130
#define NN   (130*130)       // 16900
#define NNN  (130*130*130)   // 2197000
#define NQ4  (NNN/4)         // 549250
#define NCH  12
#define XN   128
#define XNN  (XN*XN)

// R11 tiling: NO LDS / NO BARRIERS (R10) + REAL d-LOOP for I$ residency.
// Block = 16 lanes (12 valid w, +-2 DPP halo) x 16 h-rows (all valid).
// Each block walks a 26-plane d strip: 4 unrolled warmup steps, then a
// 5-step loop body executed 5x (ring slots compile-time, base = 4 mod 5),
// then 1 tail step. Hot body ~12 KB -> fits L1I, reused 5x.
#define WT   11              // w tiles: 11*12 = 132 >= 130
#define HT   9               // h tiles: 9*16 = 144 >= 130
#define DSEGS 5              // d strips: 5*26 = 130 exactly
#define NWG  (WT*HT*DSEGS)   // 495 blocks

typedef float f32x4 __attribute__((ext_vector_type(4)));

// DPP lane-shift within 16-lane rows (VALU pipe).
template <int CTRL>
__device__ __forceinline__ float dppf(float v) {
    return __int_as_float(__builtin_amdgcn_update_dpp(
        0, __float_as_int(v), CTRL, 0xF, 0xF, true));
}
#define W5(v) ((v) + dppf<0x111>(v) + dppf<0x112>(v) \
                   + dppf<0x101>(v) + dppf<0x102>(v))

// ---------------------------------------------------------------------------
// Fused kernel: conv-diff^2 + 5x5x5 replicated box + channel min/mean + exp.
//
// 12 channels = 12 orthogonal pairs of 6 shared neighbour values
//   Y0=d-, Y1=d+, Y2=h-, Y3=h+, Y4=w-, Y5=w+   (dilation-2 face neighbours)
// Per-dim addressing in box coords c in [0,129] (verified vs SH tables):
//   class  1 (center): ix = clamp(c-1,0,127), always valid
//   class -1:          ix = clamp(c-3,0,127), masked iff c==0
//   class  3:          ix = clamp(c+1,0,127), masked iff c==129
// Pairs: 0:(Y4,Y0) 1:(Y2,Y0) 2:(Y2,Y4) 3:(Y5,Y0) 4:(Y5,Y2) 5:(Y1,Y4)
//        6:(Y1,Y2) 7:(Y1,Y5) 8:(Y3,Y0) 9:(Y3,Y4) 10:(Y3,Y5) 11:(Y3,Y1)
//
// R11 vs R10 (theory: all ~100us variants share a 45-50 KB straight-line
// body that thrashes the 32 KB L1 I-cache; R8's MODE1 -- the only fast
// variant -- had a small post-DCE body):
//  1. main steps live in a REAL 5-step loop executed 5x (+1 tail), so the
//     hot ~12 KB body runs I$-warm; strips lengthened to 26 planes so the
//     loop trips 5x and warmup drops to 4/30 steps.
//  2. bijective XCD swizzle restored (R10's WRITE_SIZE 117->169 MB was
//     cross-XCD partial-line write amplification).
// ---------------------------------------------------------------------------
__global__ __launch_bounds__(256) void k_fused(const float* __restrict__ x,
                                               float* __restrict__ Cout,
                                               float* __restrict__ MV,
                                               double* __restrict__ acc,
                                               unsigned* __restrict__ gmm) {
    const int tid = threadIdx.x;
    const int wl  = tid & 15;
    const int r   = tid >> 4;

    // bijective XCD-chunk swizzle (nwg = 495 = 8*61 + 7)
    const int qq  = NWG >> 3, rm = NWG & 7;
    const int xcd = blockIdx.x & 7, idx = blockIdx.x >> 3;
    const int b   = (xcd < rm ? xcd * (qq + 1)
                              : rm * (qq + 1) + (xcd - rm) * qq) + idx;

    const int wt   = b % WT;
    const int rest = b / WT;
    const int ht   = rest % HT;
    const int ds   = rest / HT;

    const int W0 = wt * 12;
    const int H0 = ht * 16;
    const int D0 = ds * 26;

    const int  w_gl = W0 + wl - 2;                 // global w (+-2 DPP halo)
    const int  bw   = min(max(w_gl, 0), 129);      // edge-clamped box col
    const int  oh   = H0 + r;                      // output row (0..143)
    const bool valid = (wl >= 2) && (wl < 14) && (w_gl < N) && (oh < N);

    // w-dim (thread-invariant)
    const int   iwc  = min(max(bw - 1, 0), 127);
    const int   iwm  = min(max(bw - 3, 0), 127);
    const int   iwp  = min(bw + 1, 127);
    const float fw_m = (bw >= 1)   ? 1.0f : 0.0f;
    const float fw_p = (bw <= 128) ? 1.0f : 0.0f;

    // per-h-tap precompute (thread-invariant across d): box row ch first,
    // then the row clamp — required for correct oh=128,129 edges.
    int   oc[5], om[5], op[5], o4[5], o5[5];
    float fhm[5], fhp[5];
    #pragma unroll
    for (int k = 0; k < 5; ++k) {
        const int ch = min(max(oh - 2 + k, 0), 129);
        const int rc = min(max(ch - 1, 0), 127);
        const int rm2 = min(max(ch - 3, 0), 127);
        const int rp = min(ch + 1, 127);
        oc[k] = rc * XN + iwc;
        om[k] = rm2 * XN + iwc;
        op[k] = rp * XN + iwc;
        o4[k] = rc * XN + iwm;
        o5[k] = rc * XN + iwp;
        fhm[k] = (ch >= 1)   ? 1.0f : 0.0f;
        fhp[k] = (ch <= 128) ? 1.0f : 0.0f;
    }

    f32x4 ring[5][3];                   // 5-deep d ring, 12 ch as 3x f32x4
    float lsum  = 0.0f;
    float mn_mv = INFINITY, mx_mv = 0.0f;
    int   voxoff = D0 * NN + oh * N + (valid ? w_gl : 0);

#define STEP(IT, SLOT, DOUT) do {                                             \
    const int dc  = min(max(D0 - 2 + (IT), 0), 129);                          \
    const float* pc = x + (size_t)(min(max(dc - 1, 0), 127)) * XNN;           \
    const float* pm = x + (size_t)(min(max(dc - 3, 0), 127)) * XNN;           \
    const float* pp = x + (size_t)(min(dc + 1, 127)) * XNN;                   \
    const float fdm = (dc >= 1)   ? 1.0f : 0.0f;                              \
    const float fdp = (dc <= 128) ? 1.0f : 0.0f;                              \
    float HS[12];                                                             \
    _Pragma("unroll") for (int z = 0; z < 12; ++z) HS[z] = 0.0f;              \
    _Pragma("unroll") for (int k = 0; k < 5; ++k) {                           \
        const float y0 = pm[oc[k]] * fdm;                                     \
        const float y1 = pp[oc[k]] * fdp;                                     \
        const float y2 = pc[om[k]] * fhm[k];                                  \
        const float y3 = pc[op[k]] * fhp[k];                                  \
        const float y4 = pc[o4[k]] * fw_m;                                    \
        const float y5 = pc[o5[k]] * fw_p;                                    \
        float t;                                                              \
        t = y4 - y0; HS[0]  += t * t;  t = y2 - y0; HS[1]  += t * t;          \
        t = y2 - y4; HS[2]  += t * t;  t = y5 - y0; HS[3]  += t * t;          \
        t = y5 - y2; HS[4]  += t * t;  t = y1 - y4; HS[5]  += t * t;          \
        t = y1 - y2; HS[6]  += t * t;  t = y1 - y5; HS[7]  += t * t;          \
        t = y3 - y0; HS[8]  += t * t;  t = y3 - y4; HS[9]  += t * t;          \
        t = y3 - y5; HS[10] += t * t;  t = y3 - y1; HS[11] += t * t;          \
    }                                                                         \
    /* Box_w of the h-boxed values (boxes commute): 4 DPP adds per channel */ \
    _Pragma("unroll") for (int z = 0; z < 12; ++z) HS[z] = W5(HS[z]);         \
    ring[SLOT][0] = (f32x4){HS[0], HS[1], HS[2],  HS[3]};                     \
    ring[SLOT][1] = (f32x4){HS[4], HS[5], HS[6],  HS[7]};                     \
    ring[SLOT][2] = (f32x4){HS[8], HS[9], HS[10], HS[11]};                    \
    if (DOUT) {                                                               \
        f32x4 sg[3];                                                          \
        _Pragma("unroll") for (int g = 0; g < 3; ++g) {                       \
            f32x4 a = ring[0][g];                                             \
            a += ring[1][g]; a += ring[2][g];                                 \
            a += ring[3][g]; a += ring[4][g];                                 \
            sg[g] = a * (1.0f / 125.0f);                                      \
        }                                                                     \
        float sv[12];                                                         \
        _Pragma("unroll") for (int g = 0; g < 3; ++g) {                       \
            sv[4*g+0] = sg[g].x; sv[4*g+1] = sg[g].y;                         \
            sv[4*g+2] = sg[g].z; sv[4*g+3] = sg[g].w;                         \
        }                                                                     \
        float mn = sv[0], tt = sv[0];                                         \
        _Pragma("unroll") for (int z = 1; z < 12; ++z) {                      \
            mn = fminf(mn, sv[z]); tt += sv[z];                               \
        }                                                                     \
        if (valid) {                                                          \
            const float mvar = tt * (1.0f / 12.0f) - mn;                      \
            const float inv  = 1.0f / fmaxf(mvar, 1e-20f);                    \
            _Pragma("unroll") for (int z = 0; z < 12; ++z)                    \
                Cout[(size_t)z * NNN + (unsigned)voxoff] =                    \
                    __expf(-(sv[z] - mn) * inv);                              \
            MV[(unsigned)voxoff] = mvar;                                      \
            lsum += mvar;                                                     \
            mn_mv = fminf(mn_mv, mvar);                                       \
            mx_mv = fmaxf(mx_mv, mvar);                                       \
            voxoff += NN;                                                     \
        }                                                                     \
    }                                                                         \
} while (0)

    // warmup: fill ring slots 0..3 (box planes D0-2 .. D0+1, clamped)
    STEP(0, 0, false);
    STEP(1, 1, false);
    STEP(2, 2, false);
    STEP(3, 3, false);
    // main: its 4..28 in a REAL loop (5 iterations of a 5-step body;
    // base ≡ 4 mod 5 keeps ring slots compile-time), then 1 tail step.
    for (int base = 4; base < 29; base += 5) {
        STEP(base + 0, 4, true);
        STEP(base + 1, 0, true);
        STEP(base + 2, 1, true);
        STEP(base + 3, 2, true);
        STEP(base + 4, 3, true);
    }
    STEP(29, 4, true);                      // it 29, slot 29%5 = 4
#undef STEP

    // block reductions: sum, min, max of mvar (epilogue only; tiny LDS)
    __shared__ float red[256];
    red[tid] = lsum;
    __syncthreads();
    for (int st = 128; st > 0; st >>= 1) {
        if (tid < st) red[tid] += red[tid + st];
        __syncthreads();
    }
    if (tid == 0) atomicAdd(acc, (double)red[0]);
    __syncthreads();
    red[tid] = mn_mv;
    __syncthreads();
    for (int st = 128; st > 0; st >>= 1) {
        if (tid < st) red[tid] = fminf(red[tid], red[tid + st]);
        __syncthreads();
    }
    if (tid == 0) atomicMin(&gmm[0], __float_as_uint(red[0]));
    __syncthreads();
    red[tid] = mx_mv;
    __syncthreads();
    for (int st = 128; st > 0; st >>= 1) {
        if (tid < st) red[tid] = fmaxf(red[tid], red[tid + st]);
        __syncthreads();
    }
    if (tid == 0) atomicMax(&gmm[1], __float_as_uint(red[0]));
}

// zero/init the reduction cells
__global__ void k_zero(double* acc, unsigned* gmm) {
    if (blockIdx.x == 0 && threadIdx.x == 0) {
        *acc = 0.0;
        gmm[0] = 0xFFFFFFFFu;
        gmm[1] = 0u;
    }
}

// k_fix: apply the global-mean clip only where it binds (uniform early-out
// when it never does). Pass 1 wrote out = exp(-mind/max(mvar,1e-20));
// clipped-correct value is out^(mvar_used/mvar_clipped).
__global__ __launch_bounds__(256) void k_fix(float* __restrict__ io,
                                             const float* __restrict__ MV,
                                             const double* __restrict__ acc,
                                             const unsigned* __restrict__ gmm) {
    const float mv_mean = (float)(*acc * (1.0 / (double)NNN));
    const float lo = mv_mean * 0.001f, hi = mv_mean * 1000.0f;
    const float gmin = __uint_as_float(gmm[0]);
    const float gmax = __uint_as_float(gmm[1]);
    if (gmin >= lo && gmax <= hi) return;
    for (int q = blockIdx.x * 256 + threadIdx.x; q < NQ4;
         q += gridDim.x * 256) {
        const f32x4 mv = *((const f32x4*)MV + q);
        #pragma unroll
        for (int k = 0; k < 4; ++k) {
            const float used = fmaxf(mv[k], 1e-20f);
            const float cl   = fminf(fmaxf(mv[k], lo), hi);
            const float e    = used / cl;
            if (fabsf(e - 1.0f) > 1e-6f) {
                const size_t vox = (size_t)q * 4 + k;
                #pragma unroll
                for (int o = 0; o < NCH; ++o) {
                    const float v = io[(size_t)o * NNN + vox];
                    if (v > 0.0f)
                        io[(size_t)o * NNN + vox] = __powf(v, e);
                }
            }
        }
    }
}

extern "C" void kernel_launch(void* const* d_in, const int* in_sizes, int n_in,
                              void* d_out, int out_size, void* d_ws, size_t ws_size,
                              hipStream_t stream) {
    const float* x = (const float*)d_in[0];
    float* out = (float*)d_out;                 // [12,130,130,130] f32
    float* MV  = (float*)d_ws;                  // mvar plane, NNN floats
    double*  acc = (double*)((char*)d_ws + (size_t)NNN * sizeof(float));
    unsigned* gmm = (unsigned*)((char*)d_ws + (size_t)NNN * sizeof(float) + 8);

    k_zero <<<1, 64, 0, stream>>>(acc, gmm);
    k_fused<<<NWG, 256, 0, stream>>>(x, out, MV, acc, gmm);  // 495 blocks
    k_fix  <<<1024, 256, 0, stream>>>(out, MV, acc, gmm);
}